// Round 7
// baseline (159.088 us; speedup 1.0000x reference)
//
#include <hip/hip_runtime.h>
#include <hip/hip_bf16.h>
#include <stdint.h>

// GraphUnet forward, N=4096 nodes, D=128, E=131072 edges, K=2457 kept.
// Full CSR by src (one build, used by 2-hop union AND up-prop gather);
// bitset 2-hop; wave-parallel exact-rank top-k; pooled GCN as bf16 MFMA
// GEMM over a binary matrix; register-tiled DxD GEMMs.

#define NN 4096
#define DD 128
#define KKEEP 2457              // int(0.6*4096)
#define SUBW 40                 // ceil(KKEEP/64)
#define MP 2464                 // KKEEP padded to 16 (M tiles = 154)
#define KP 2560                 // KKEEP padded to SUBW*64 (80 k-steps of 32)
#define MT 154
#define NT 8
#define SPLITK 4
#define KCHUNK (KP / SPLITK)    // 640 -> 20 mfma steps per wave
#define RT 8                    // row tile for DxD gemms

typedef unsigned long long u64;
typedef unsigned short ushort_t;
typedef __attribute__((ext_vector_type(8))) short bf16x8;
typedef __attribute__((ext_vector_type(4))) float f32x4;

// rowbits atomicOr + full out-degree histogram, one pass over edges
__global__ void k_build_bits(const int* __restrict__ g, int E,
                             u64* __restrict__ rowbits, int* __restrict__ deg) {
    int e = blockIdx.x * 256 + threadIdx.x;
    if (e >= E) return;
    int s = g[e], d2 = g[E + e];
    atomicOr(&rowbits[(size_t)s * 64 + (d2 >> 6)], 1ull << (d2 & 63));
    atomicAdd(&deg[s], 1);
}

// exclusive scan of deg[NN] -> off[NN+1]; single block of 256 threads x 16 each
__global__ void k_scan(const int* __restrict__ deg, int* __restrict__ off) {
    __shared__ int part[256];
    int t = threadIdx.x;
    int base = t * 16;
    int loc[16]; int s = 0;
    #pragma unroll
    for (int i = 0; i < 16; ++i) { loc[i] = s; s += deg[base + i]; }
    part[t] = s;
    __syncthreads();
    int sum = 0;
    for (int i = 0; i < t; ++i) sum += part[i];
    #pragma unroll
    for (int i = 0; i < 16; ++i) off[base + i] = sum + loc[i];
    if (t == 255) off[NN] = sum + s;
}

// scatter ALL edges: csr[off[s] + cursor[s]++] = dst
__global__ void k_scatter(const int* __restrict__ g, int E, const int* __restrict__ off,
                          int* __restrict__ cursor, int* __restrict__ csr) {
    int e = blockIdx.x * 256 + threadIdx.x;
    if (e >= E) return;
    int s = g[e];
    int p = atomicAdd(&cursor[s], 1);
    csr[off[s] + p] = g[E + e];
}

// h0 = h @ Wd + bd, RT rows per block, Wd k-slices in registers
__global__ void k_h0(const float* __restrict__ h, const float* __restrict__ Wd,
                     const float* __restrict__ bd, float* __restrict__ h0) {
    __shared__ float rows[RT][DD];
    int d = threadIdx.x;
    int r0 = blockIdx.x * RT;
    #pragma unroll
    for (int r = 0; r < RT; ++r) rows[r][d] = h[(size_t)(r0 + r) * DD + d];
    __syncthreads();
    float acc[RT];
    float b = bd[d];
    #pragma unroll
    for (int r = 0; r < RT; ++r) acc[r] = b;
    for (int kb = 0; kb < DD; kb += 16) {
        float w[16];
        #pragma unroll
        for (int j = 0; j < 16; ++j) w[j] = Wd[(size_t)(kb + j) * DD + d];
        #pragma unroll
        for (int r = 0; r < RT; ++r)
            #pragma unroll
            for (int j = 0; j < 16; ++j) acc[r] += rows[r][kb + j] * w[j];
    }
    #pragma unroll
    for (int r = 0; r < RT; ++r) h0[(size_t)(r0 + r) * DD + d] = acc[r];
}

// scores = sigmoid(h0 @ pw + pb)
__global__ void k_score(const float* __restrict__ h0, const float* __restrict__ pw,
                        const float* __restrict__ pb, float* __restrict__ scores) {
    __shared__ float red[DD];
    int r = blockIdx.x, tid = threadIdx.x;
    red[tid] = h0[(size_t)r * DD + tid] * pw[tid];
    __syncthreads();
    for (int sft = 64; sft > 0; sft >>= 1) {
        if (tid < sft) red[tid] += red[tid + sft];
        __syncthreads();
    }
    if (tid == 0) scores[r] = 1.0f / (1.0f + expf(-(red[0] + pb[0])));
}

// Exact top-k rank, one wave per node i. rank = #{j: s_j>s_i or (s_j==s_i, j<i)}.
__global__ void k_rank(const float* __restrict__ scores, int* __restrict__ keep,
                       int* __restrict__ pos, int* __restrict__ idxl) {
    int lane = threadIdx.x & 63;
    int i = blockIdx.x * 4 + (threadIdx.x >> 6);
    float my = scores[i];
    int rank = 0;
    #pragma unroll 4
    for (int base = 0; base < NN; base += 64) {
        int jj = base + lane;
        float sj = scores[jj];
        u64 m = __ballot((sj > my) || (sj == my && jj < i));
        rank += __popcll(m);
    }
    if (lane == 0) {
        if (rank < KKEEP) { keep[i] = 1; pos[i] = rank; idxl[rank] = i; }
        else keep[i] = 0;
    }
}

// reach2[i] = union over CSR out-neighbors of rowbits rows; project to kept cols.
__global__ void k_sub(const u64* __restrict__ rowbits, const int* __restrict__ off,
                      const int* __restrict__ csr, const int* __restrict__ idxl,
                      u64* __restrict__ subbits, float* __restrict__ invdeg) {
    int wave = threadIdx.x >> 6, lane = threadIdx.x & 63;
    int r = blockIdx.x * 4 + wave;
    if (r >= KKEEP) return;
    int i = idxl[r];
    int e = off[i], e1 = off[i + 1];
    u64 acc = 0;
    for (; e + 4 <= e1; e += 4) {
        int n0 = csr[e], n1 = csr[e + 1], n2 = csr[e + 2], n3 = csr[e + 3];
        u64 a = rowbits[(size_t)n0 * 64 + lane];
        u64 b = rowbits[(size_t)n1 * 64 + lane];
        u64 c = rowbits[(size_t)n2 * 64 + lane];
        u64 d = rowbits[(size_t)n3 * 64 + lane];
        acc |= (a | b) | (c | d);
    }
    for (; e < e1; ++e) acc |= rowbits[(size_t)csr[e] * 64 + lane];
    int cnt = 0;
    for (int wj = 0; wj < SUBW; ++wj) {
        int c = wj * 64 + lane;
        int ci = (c < KKEEP) ? idxl[c] : 0;
        u64 w = __shfl(acc, ci >> 6);
        int bit = (c < KKEEP) ? (int)((w >> (ci & 63)) & 1ull) : 0;
        u64 word = __ballot(bit);
        cnt += __popcll(word);
        if (lane == 0) subbits[(size_t)r * SUBW + wj] = word;
    }
    if (lane == 0) invdeg[r] = 1.0f / (float)cnt;
}

// Expand subbits -> dense bf16 binary matrix S [MP][KP] (1.0 or 0.0).
__global__ void k_expand(const u64* __restrict__ subbits, short* __restrict__ S) {
    int r = blockIdx.x;
    int t = threadIdx.x;
    u64* Srow = (u64*)(S + (size_t)r * KP);
    bool live = (r < KKEEP);
    #pragma unroll
    for (int i = 0; i < 2; ++i) {
        int q = t + i * 320;
        if (q >= KP / 4) break;
        u64 outw = 0;
        if (live) {
            int c0 = q * 4;
            u64 w = subbits[(size_t)r * SUBW + (c0 >> 6)];
            int sh = c0 & 63;
            if ((w >> sh) & 1)       outw |= 0x3F80ull;
            if ((w >> (sh + 1)) & 1) outw |= 0x3F80ull << 16;
            if ((w >> (sh + 2)) & 1) outw |= 0x3F80ull << 32;
            if ((w >> (sh + 3)) & 1) outw |= 0x3F80ull << 48;
        }
        Srow[q] = outw;
    }
}

// t'[c] = (h0[idx[c]]*scores[idx[c]]) @ Wb * invdeg[c], transposed bf16 [DD][KP].
// Grid covers KP/RT blocks so pad columns get zeroed (no memset needed).
__global__ void k_t(const float* __restrict__ h0, const float* __restrict__ scores,
                    const int* __restrict__ idxl, const float* __restrict__ Wb,
                    const float* __restrict__ invdeg, ushort_t* __restrict__ tT) {
    __shared__ float rows[RT][DD];
    int d = threadIdx.x;
    int r0 = blockIdx.x * RT;
    #pragma unroll
    for (int r = 0; r < RT; ++r) {
        int rr = r0 + r;
        float v = 0.f;
        if (rr < KKEEP) {
            int i = idxl[rr];
            v = h0[(size_t)i * DD + d] * scores[i];
        }
        rows[r][d] = v;
    }
    __syncthreads();
    float acc[RT];
    #pragma unroll
    for (int r = 0; r < RT; ++r) acc[r] = 0.f;
    for (int kb = 0; kb < DD; kb += 16) {
        float w[16];
        #pragma unroll
        for (int j = 0; j < 16; ++j) w[j] = Wb[(size_t)(kb + j) * DD + d];
        #pragma unroll
        for (int r = 0; r < RT; ++r)
            #pragma unroll
            for (int j = 0; j < 16; ++j) acc[r] += rows[r][kb + j] * w[j];
    }
    bf16x8 packed;
    #pragma unroll
    for (int r = 0; r < RT; ++r) {
        int rr = r0 + r;
        float v = (rr < KKEEP) ? acc[r] * invdeg[rr] : 0.f;
        __hip_bfloat16 b = __float2bfloat16(v);
        packed[r] = *reinterpret_cast<short*>(&b);
    }
    *reinterpret_cast<bf16x8*>(tT + (size_t)d * KP + r0) = packed;
}

// hb = S @ t' via 16x16x32 bf16 MFMA, split-K=4 with f32 atomics.
__global__ void k_gemm(const short* __restrict__ S, const short* __restrict__ tT,
                       float* __restrict__ hb) {
    int wid = blockIdx.x * 4 + (threadIdx.x >> 6);
    int lane = threadIdx.x & 63;
    int tile = wid % (MT * NT);
    int sk = wid / (MT * NT);
    int rt = tile >> 3, ct = tile & 7;
    const short* arow = S + (size_t)(rt * 16 + (lane & 15)) * KP + ((lane >> 4) * 8) + sk * KCHUNK;
    const short* brow = tT + (size_t)(ct * 16 + (lane & 15)) * KP + ((lane >> 4) * 8) + sk * KCHUNK;
    f32x4 acc = {0.f, 0.f, 0.f, 0.f};
    #pragma unroll 4
    for (int kk = 0; kk < KCHUNK; kk += 32) {
        bf16x8 a = *(const bf16x8*)(arow + kk);
        bf16x8 b = *(const bf16x8*)(brow + kk);
        acc = __builtin_amdgcn_mfma_f32_16x16x32_bf16(a, b, acc, 0, 0, 0);
    }
    int col = ct * 16 + (lane & 15);
    int row0 = rt * 16 + ((lane >> 4) * 4);
    #pragma unroll
    for (int j = 0; j < 4; ++j) {
        int row = row0 + j;
        if (row < KKEEP) atomicAdd(&hb[(size_t)row * DD + col], acc[j]);
    }
}

// uu[r] = (hb[r] + bb) @ Wu
__global__ void k_u(const float* __restrict__ hb, const float* __restrict__ bb,
                    const float* __restrict__ Wu, float* __restrict__ uu) {
    __shared__ float rows[RT][DD];
    int d = threadIdx.x;
    int r0 = blockIdx.x * RT;
    float bias = bb[d];
    #pragma unroll
    for (int r = 0; r < RT; ++r) {
        int rr = r0 + r;
        rows[r][d] = (rr < KKEEP) ? hb[(size_t)rr * DD + d] + bias : 0.f;
    }
    __syncthreads();
    float acc[RT];
    #pragma unroll
    for (int r = 0; r < RT; ++r) acc[r] = 0.f;
    for (int kb = 0; kb < DD; kb += 16) {
        float w[16];
        #pragma unroll
        for (int j = 0; j < 16; ++j) w[j] = Wu[(size_t)(kb + j) * DD + d];
        #pragma unroll
        for (int r = 0; r < RT; ++r)
            #pragma unroll
            for (int j = 0; j < 16; ++j) acc[r] += rows[r][kb + j] * w[j];
    }
    #pragma unroll
    for (int r = 0; r < RT; ++r) {
        int rr = r0 + r;
        if (rr < KKEEP) uu[(size_t)rr * DD + d] = acc[r];
    }
}

// out rows: hup[s] = sum over CSR (kept dst) of uu rows; out1/out2 fused.
__global__ void k_agg(const int* __restrict__ off, const int* __restrict__ csr,
                      const int* __restrict__ keep, const int* __restrict__ pos,
                      const float* __restrict__ uu, const float* __restrict__ bu,
                      const float* __restrict__ h0, const float* __restrict__ h,
                      float* __restrict__ out) {
    int s = blockIdx.x, d = threadIdx.x;
    int b = off[s], e2 = off[s + 1];
    float acc = 0.f;
    for (int k = b; k < e2; ++k) {
        int dst = csr[k];
        if (keep[dst]) acc += uu[(size_t)pos[dst] * DD + d];
    }
    size_t o = (size_t)s * DD + d;
    float a = acc + bu[d] + h0[o];
    out[o] = a;
    out[(size_t)NN * DD + o] = a + h[o];
}

extern "C" void kernel_launch(void* const* d_in, const int* in_sizes, int n_in,
                              void* d_out, int out_size, void* d_ws, size_t ws_size,
                              hipStream_t stream) {
    const int*   g  = (const int*)d_in[0];
    const float* h  = (const float*)d_in[1];
    const float* Wd = (const float*)d_in[2];
    const float* bd = (const float*)d_in[3];
    const float* pw = (const float*)d_in[4];
    const float* pb = (const float*)d_in[5];
    const float* Wb = (const float*)d_in[6];
    const float* bb = (const float*)d_in[7];
    const float* Wu = (const float*)d_in[8];
    const float* bu = (const float*)d_in[9];
    float* out = (float*)d_out;
    const int E = in_sizes[0] / 2;

    char* ws = (char*)d_ws;
    // S [0,12.6MB): rowbits [0,2MB) dies after k_sub, before k_expand writes S;
    // uu reuses [0,1.3MB) after k_gemm has consumed S.
    short*    S       = (short*)(ws + 0);
    u64*      rowbits = (u64*)  (ws + 0);
    float*    uu      = (float*)(ws + 0);
    u64*      subbits = (u64*)  (ws + (13u << 20));   // 786 KB
    float*    h0      = (float*)(ws + (14u << 20));   // 2 MB
    ushort_t* tT      = (ushort_t*)(ws + (18u << 20));// 656 KB
    float*    hb      = (float*)(ws + (19u << 20));   // 1.26 MB, ends 21180928
    int*      csr     = (int*)  (ws + 21180928u);     // 512 KB (all E edges)
    float*    scores  = (float*)(ws + (22u << 20));
    float*    invdeg  = (float*)(ws + (22u << 20) + 16384);
    int*      pos     = (int*)  (ws + (22u << 20) + 32768);
    int*      keep    = (int*)  (ws + (22u << 20) + 49152);
    int*      idxl    = (int*)  (ws + (22u << 20) + 65536);
    int*      deg     = (int*)  (ws + (22u << 20) + 81920);
    int*      cursor  = (int*)  (ws + (22u << 20) + 98304);
    int*      off     = (int*)  (ws + (22u << 20) + 114688); // NN+1 ints

    (void)hipMemsetAsync(rowbits, 0, (2u << 20), stream);
    (void)hipMemsetAsync(hb, 0, (size_t)KKEEP * DD * sizeof(float), stream);
    (void)hipMemsetAsync(deg, 0, 2 * 16384, stream);   // deg + cursor contiguous

    k_build_bits<<<(E + 255) / 256, 256, 0, stream>>>(g, E, rowbits, deg);
    k_scan<<<1, 256, 0, stream>>>(deg, off);
    k_scatter<<<(E + 255) / 256, 256, 0, stream>>>(g, E, off, cursor, csr);
    k_h0<<<NN / RT, DD, 0, stream>>>(h, Wd, bd, h0);
    k_score<<<NN, DD, 0, stream>>>(h0, pw, pb, scores);
    k_rank<<<NN / 4, 256, 0, stream>>>(scores, keep, pos, idxl);
    k_sub<<<(KKEEP + 3) / 4, 256, 0, stream>>>(rowbits, off, csr, idxl, subbits, invdeg);
    k_expand<<<MP, 320, 0, stream>>>(subbits, S);
    k_t<<<KP / RT, DD, 0, stream>>>(h0, scores, idxl, Wb, invdeg, tT);
    k_gemm<<<(MT * NT * SPLITK) / 4, 256, 0, stream>>>(S, (const short*)tT, hb);
    k_u<<<(KKEEP + RT - 1) / RT, DD, 0, stream>>>(hb, bb, Wu, uu);
    k_agg<<<NN, DD, 0, stream>>>(off, csr, keep, pos, uu, bu, h0, h, out);
}

// Round 8
// 154.002 us; speedup vs baseline: 1.0330x; 1.0330x over previous
//
#include <hip/hip_runtime.h>
#include <hip/hip_bf16.h>
#include <stdint.h>

// GraphUnet forward, N=4096 nodes, D=128, E=131072 edges, K=2457 kept.
// CSR by src; bitset 2-hop with direct dense-bf16 S emission; fused
// h0+score; wave-parallel exact-rank top-k; full-K MFMA pooled GEMM;
// CSR gather up-prop fused with final adds. 12 dispatches.

#define NN 4096
#define DD 128
#define KKEEP 2457              // int(0.6*4096)
#define SUBW 40                 // ceil(KKEEP/64)
#define MP 2464                 // KKEEP padded to 16 (M tiles = 154)
#define KP 2560                 // KKEEP padded to SUBW*64
#define MT 154
#define NT 8
#define RT 8                    // row tile for DxD gemms

typedef unsigned long long u64;
typedef unsigned short ushort_t;
typedef __attribute__((ext_vector_type(8))) short bf16x8;
typedef __attribute__((ext_vector_type(4))) float f32x4;

// rowbits atomicOr + out-degree histogram, one pass over edges
__global__ void k_build_bits(const int* __restrict__ g, int E,
                             u64* __restrict__ rowbits, int* __restrict__ deg) {
    int e = blockIdx.x * 256 + threadIdx.x;
    if (e >= E) return;
    int s = g[e], d2 = g[E + e];
    atomicOr(&rowbits[(size_t)s * 64 + (d2 >> 6)], 1ull << (d2 & 63));
    atomicAdd(&deg[s], 1);
}

// exclusive scan of deg[NN] -> off[NN+1]; single block
__global__ void k_scan(const int* __restrict__ deg, int* __restrict__ off) {
    __shared__ int part[256];
    int t = threadIdx.x;
    int base = t * 16;
    int loc[16]; int s = 0;
    #pragma unroll
    for (int i = 0; i < 16; ++i) { loc[i] = s; s += deg[base + i]; }
    part[t] = s;
    __syncthreads();
    int sum = 0;
    for (int i = 0; i < t; ++i) sum += part[i];
    #pragma unroll
    for (int i = 0; i < 16; ++i) off[base + i] = sum + loc[i];
    if (t == 255) off[NN] = sum + s;
}

// h0 = h @ Wd + bd (RT rows/block) + fused scores = sigmoid(h0 @ pw + pb)
__global__ void k_h0(const float* __restrict__ h, const float* __restrict__ Wd,
                     const float* __restrict__ bd, const float* __restrict__ pw,
                     const float* __restrict__ pb, float* __restrict__ h0,
                     float* __restrict__ scores) {
    __shared__ float rows[RT][DD];
    __shared__ float sred[2][RT];
    int d = threadIdx.x;
    int r0 = blockIdx.x * RT;
    #pragma unroll
    for (int r = 0; r < RT; ++r) rows[r][d] = h[(size_t)(r0 + r) * DD + d];
    __syncthreads();
    float acc[RT];
    float b = bd[d];
    #pragma unroll
    for (int r = 0; r < RT; ++r) acc[r] = b;
    for (int kb = 0; kb < DD; kb += 16) {
        float w[16];
        #pragma unroll
        for (int j = 0; j < 16; ++j) w[j] = Wd[(size_t)(kb + j) * DD + d];
        #pragma unroll
        for (int r = 0; r < RT; ++r)
            #pragma unroll
            for (int j = 0; j < 16; ++j) acc[r] += rows[r][kb + j] * w[j];
    }
    #pragma unroll
    for (int r = 0; r < RT; ++r) h0[(size_t)(r0 + r) * DD + d] = acc[r];
    // fused score: dot(h0 row, pw) reduced across the block
    float pwd = pw[d];
    int lane = d & 63, wv = d >> 6;
    #pragma unroll
    for (int r = 0; r < RT; ++r) {
        float v = acc[r] * pwd;
        #pragma unroll
        for (int s = 32; s > 0; s >>= 1) v += __shfl_xor(v, s);
        if (lane == 0) sred[wv][r] = v;
    }
    __syncthreads();
    if (d < RT) {
        float v = sred[0][d] + sred[1][d];
        scores[r0 + d] = 1.0f / (1.0f + expf(-(v + pb[0])));
    }
}

// Exact top-k rank, one wave per node i. rank = #{j: s_j>s_i or (s_j==s_i, j<i)}.
__global__ void k_rank(const float* __restrict__ scores, int* __restrict__ keep,
                       int* __restrict__ pos, int* __restrict__ idxl) {
    int lane = threadIdx.x & 63;
    int i = blockIdx.x * 4 + (threadIdx.x >> 6);
    float my = scores[i];
    int rank = 0;
    #pragma unroll 4
    for (int base = 0; base < NN; base += 64) {
        int jj = base + lane;
        float sj = scores[jj];
        u64 m = __ballot((sj > my) || (sj == my && jj < i));
        rank += __popcll(m);
    }
    if (lane == 0) {
        if (rank < KKEEP) { keep[i] = 1; pos[i] = rank; idxl[rank] = i; }
        else keep[i] = 0;
    }
}

// scatter edges: csr = raw dst (for k_sub), csrv = keep ? pos : -1 (for k_agg)
__global__ void k_scatter(const int* __restrict__ g, int E, const int* __restrict__ off,
                          const int* __restrict__ keep, const int* __restrict__ pos,
                          int* __restrict__ cursor, int* __restrict__ csr,
                          int* __restrict__ csrv) {
    int e = blockIdx.x * 256 + threadIdx.x;
    if (e >= E) return;
    int s = g[e], dd = g[E + e];
    int p = atomicAdd(&cursor[s], 1);
    int o = off[s] + p;
    csr[o] = dd;
    csrv[o] = keep[dd] ? pos[dd] : -1;
}

// reach2 union over CSR neighbors; project to kept cols; write dense bf16 S row.
__global__ void k_sub(const u64* __restrict__ rowbits, const int* __restrict__ off,
                      const int* __restrict__ csr, const int* __restrict__ idxl,
                      ushort_t* __restrict__ S, float* __restrict__ invdeg) {
    int wave = threadIdx.x >> 6, lane = threadIdx.x & 63;
    int r = blockIdx.x * 4 + wave;          // r < MP (grid covers pads)
    ushort_t* Srow = S + (size_t)r * KP;
    if (r >= KKEEP) {
        for (int wj = 0; wj < SUBW; ++wj) Srow[wj * 64 + lane] = 0;
        return;
    }
    int i = idxl[r];
    int e = off[i], e1 = off[i + 1];
    u64 acc = 0;
    for (; e + 4 <= e1; e += 4) {
        int n0 = csr[e], n1 = csr[e + 1], n2 = csr[e + 2], n3 = csr[e + 3];
        u64 a = rowbits[(size_t)n0 * 64 + lane];
        u64 b = rowbits[(size_t)n1 * 64 + lane];
        u64 c = rowbits[(size_t)n2 * 64 + lane];
        u64 d = rowbits[(size_t)n3 * 64 + lane];
        acc |= (a | b) | (c | d);
    }
    for (; e < e1; ++e) acc |= rowbits[(size_t)csr[e] * 64 + lane];
    int cnt = 0;
    for (int wj = 0; wj < SUBW; ++wj) {
        int c = wj * 64 + lane;
        int ci = (c < KKEEP) ? idxl[c] : 0;
        u64 w = __shfl(acc, ci >> 6);
        int bit = (c < KKEEP) ? (int)((w >> (ci & 63)) & 1ull) : 0;
        cnt += __popcll(__ballot(bit));
        Srow[c] = bit ? 0x3F80 : 0;
    }
    if (lane == 0) invdeg[r] = 1.0f / (float)cnt;
}

// t'[c] = (h0[idx[c]]*scores[idx[c]]) @ Wb * invdeg[c], transposed bf16 [DD][KP].
__global__ void k_t(const float* __restrict__ h0, const float* __restrict__ scores,
                    const int* __restrict__ idxl, const float* __restrict__ Wb,
                    const float* __restrict__ invdeg, ushort_t* __restrict__ tT) {
    __shared__ float rows[RT][DD];
    int d = threadIdx.x;
    int r0 = blockIdx.x * RT;
    #pragma unroll
    for (int r = 0; r < RT; ++r) {
        int rr = r0 + r;
        float v = 0.f;
        if (rr < KKEEP) {
            int i = idxl[rr];
            v = h0[(size_t)i * DD + d] * scores[i];
        }
        rows[r][d] = v;
    }
    __syncthreads();
    float acc[RT];
    #pragma unroll
    for (int r = 0; r < RT; ++r) acc[r] = 0.f;
    for (int kb = 0; kb < DD; kb += 16) {
        float w[16];
        #pragma unroll
        for (int j = 0; j < 16; ++j) w[j] = Wb[(size_t)(kb + j) * DD + d];
        #pragma unroll
        for (int r = 0; r < RT; ++r)
            #pragma unroll
            for (int j = 0; j < 16; ++j) acc[r] += rows[r][kb + j] * w[j];
    }
    bf16x8 packed;
    #pragma unroll
    for (int r = 0; r < RT; ++r) {
        int rr = r0 + r;
        float v = (rr < KKEEP) ? acc[r] * invdeg[rr] : 0.f;
        __hip_bfloat16 b = __float2bfloat16(v);
        packed[r] = *reinterpret_cast<short*>(&b);
    }
    *reinterpret_cast<bf16x8*>(tT + (size_t)d * KP + r0) = packed;
}

// hb = S @ t' via 16x16x32 bf16 MFMA, full K per wave, direct stores.
__global__ void k_gemm(const short* __restrict__ S, const short* __restrict__ tT,
                       float* __restrict__ hb) {
    int wid = blockIdx.x * 4 + (threadIdx.x >> 6);   // 0..MT*NT-1
    int lane = threadIdx.x & 63;
    int rt = wid >> 3, ct = wid & 7;
    const short* arow = S + (size_t)(rt * 16 + (lane & 15)) * KP + ((lane >> 4) * 8);
    const short* brow = tT + (size_t)(ct * 16 + (lane & 15)) * KP + ((lane >> 4) * 8);
    f32x4 acc = {0.f, 0.f, 0.f, 0.f};
    #pragma unroll 4
    for (int kk = 0; kk < KP; kk += 32) {
        bf16x8 a = *(const bf16x8*)(arow + kk);
        bf16x8 b = *(const bf16x8*)(brow + kk);
        acc = __builtin_amdgcn_mfma_f32_16x16x32_bf16(a, b, acc, 0, 0, 0);
    }
    int col = ct * 16 + (lane & 15);
    int row0 = rt * 16 + ((lane >> 4) * 4);
    #pragma unroll
    for (int j = 0; j < 4; ++j) {
        int row = row0 + j;
        if (row < KKEEP) hb[(size_t)row * DD + col] = acc[j];
    }
}

// uu[r] = (hb[r] + bb) @ Wu
__global__ void k_u(const float* __restrict__ hb, const float* __restrict__ bb,
                    const float* __restrict__ Wu, float* __restrict__ uu) {
    __shared__ float rows[RT][DD];
    int d = threadIdx.x;
    int r0 = blockIdx.x * RT;
    float bias = bb[d];
    #pragma unroll
    for (int r = 0; r < RT; ++r) {
        int rr = r0 + r;
        rows[r][d] = (rr < KKEEP) ? hb[(size_t)rr * DD + d] + bias : 0.f;
    }
    __syncthreads();
    float acc[RT];
    #pragma unroll
    for (int r = 0; r < RT; ++r) acc[r] = 0.f;
    for (int kb = 0; kb < DD; kb += 16) {
        float w[16];
        #pragma unroll
        for (int j = 0; j < 16; ++j) w[j] = Wu[(size_t)(kb + j) * DD + d];
        #pragma unroll
        for (int r = 0; r < RT; ++r)
            #pragma unroll
            for (int j = 0; j < 16; ++j) acc[r] += rows[r][kb + j] * w[j];
    }
    #pragma unroll
    for (int r = 0; r < RT; ++r) {
        int rr = r0 + r;
        if (rr < KKEEP) uu[(size_t)rr * DD + d] = acc[r];
    }
}

// out rows: hup[s] = sum over csrv>=0 of uu rows; out1/out2 fused.
__global__ void k_agg(const int* __restrict__ off, const int* __restrict__ csrv,
                      const float* __restrict__ uu, const float* __restrict__ bu,
                      const float* __restrict__ h0, const float* __restrict__ h,
                      float* __restrict__ out) {
    int s = blockIdx.x, d = threadIdx.x;
    int b = off[s], e2 = off[s + 1];
    float acc = 0.f;
    for (int k = b; k < e2; ++k) {
        int v = csrv[k];
        if (v >= 0) acc += uu[(size_t)v * DD + d];
    }
    size_t o = (size_t)s * DD + d;
    float a = acc + bu[d] + h0[o];
    out[o] = a;
    out[(size_t)NN * DD + o] = a + h[o];
}

extern "C" void kernel_launch(void* const* d_in, const int* in_sizes, int n_in,
                              void* d_out, int out_size, void* d_ws, size_t ws_size,
                              hipStream_t stream) {
    const int*   g  = (const int*)d_in[0];
    const float* h  = (const float*)d_in[1];
    const float* Wd = (const float*)d_in[2];
    const float* bd = (const float*)d_in[3];
    const float* pw = (const float*)d_in[4];
    const float* pb = (const float*)d_in[5];
    const float* Wb = (const float*)d_in[6];
    const float* bb = (const float*)d_in[7];
    const float* Wu = (const float*)d_in[8];
    const float* bu = (const float*)d_in[9];
    float* out = (float*)d_out;
    const int E = in_sizes[0] / 2;

    char* ws = (char*)d_ws;
    // S [0, 12.6MB) live k_sub..k_gemm; uu reuses [0,1.3MB) after k_gemm.
    ushort_t* S       = (ushort_t*)(ws + 0);
    float*    uu      = (float*)(ws + 0);
    u64*      rowbits = (u64*)  (ws + (13u << 20));   // 2 MB
    float*    h0      = (float*)(ws + (15u << 20));   // 2 MB
    ushort_t* tT      = (ushort_t*)(ws + (17u << 20));// 656 KB
    float*    hb      = (float*)(ws + (18u << 20));   // 1.26 MB
    int*      csr     = (int*)  (ws + (20u << 20));   // 512 KB
    int*      csrv    = (int*)  (ws + (20u << 20) + 524288); // 512 KB
    float*    scores  = (float*)(ws + (21u << 20));
    float*    invdeg  = (float*)(ws + (21u << 20) + 16384);
    int*      pos     = (int*)  (ws + (21u << 20) + 32768);
    int*      keep    = (int*)  (ws + (21u << 20) + 49152);
    int*      idxl    = (int*)  (ws + (21u << 20) + 65536);
    int*      deg     = (int*)  (ws + (21u << 20) + 81920);
    int*      cursor  = (int*)  (ws + (21u << 20) + 98304);
    int*      off     = (int*)  (ws + (21u << 20) + 114688); // NN+1 ints

    (void)hipMemsetAsync(rowbits, 0, (2u << 20), stream);
    (void)hipMemsetAsync(deg, 0, 2 * 16384, stream);   // deg + cursor contiguous

    k_build_bits<<<(E + 255) / 256, 256, 0, stream>>>(g, E, rowbits, deg);
    k_scan<<<1, 256, 0, stream>>>(deg, off);
    k_h0<<<NN / RT, DD, 0, stream>>>(h, Wd, bd, pw, pb, h0, scores);
    k_rank<<<NN / 4, 256, 0, stream>>>(scores, keep, pos, idxl);
    k_scatter<<<(E + 255) / 256, 256, 0, stream>>>(g, E, off, keep, pos, cursor, csr, csrv);
    k_sub<<<MP / 4, 256, 0, stream>>>(rowbits, off, csr, idxl, S, invdeg);
    k_t<<<KP / RT, DD, 0, stream>>>(h0, scores, idxl, Wb, invdeg, tT);
    k_gemm<<<(MT * NT) / 4, 256, 0, stream>>>((const short*)S, (const short*)tT, hb);
    k_u<<<(KKEEP + RT - 1) / RT, DD, 0, stream>>>(hb, bb, Wu, uu);
    k_agg<<<NN, DD, 0, stream>>>(off, csrv, uu, bu, h0, h, out);
}

// Round 9
// 149.621 us; speedup vs baseline: 1.0633x; 1.0293x over previous
//
#include <hip/hip_runtime.h>
#include <hip/hip_bf16.h>
#include <stdint.h>

// GraphUnet forward, N=4096 nodes, D=128, E=131072 edges, K=2457 kept.
// 8 dispatches: memset | h0+score||build_bits | rank||scan | sub||scatter |
// t | gemm | u | agg. Bitset 2-hop (bit-walk), dense bf16 S emission,
// full-K MFMA pooled GEMM, CSR gather up-prop fused with final adds.

#define NN 4096
#define DD 128
#define KKEEP 2457              // int(0.6*4096)
#define SUBW 40                 // ceil(KKEEP/64)
#define MP 2464                 // KKEEP padded to 16 (M tiles = 154)
#define KP 2560                 // KKEEP padded to SUBW*64
#define MT 154
#define NT 8
#define RT 8                    // row tile for DxD gemms

typedef unsigned long long u64;
typedef unsigned short ushort_t;
typedef __attribute__((ext_vector_type(8))) short bf16x8;
typedef __attribute__((ext_vector_type(4))) float f32x4;

// ---- fused: blocks [0,512) h0+score ; blocks [512,1536) build_bits ----
__global__ void k_h0_build(const float* __restrict__ h, const float* __restrict__ Wd,
                           const float* __restrict__ bd, const float* __restrict__ pw,
                           const float* __restrict__ pb, const int* __restrict__ g, int E,
                           float* __restrict__ h0, float* __restrict__ scores,
                           u64* __restrict__ rowbits, int* __restrict__ deg) {
    __shared__ float rows[RT][DD];
    __shared__ float sred[2][RT];
    int bid = blockIdx.x;
    int d = threadIdx.x;
    if (bid >= NN / RT) {
        int e = (bid - NN / RT) * 128 + d;
        if (e < E) {
            int s = g[e], d2 = g[E + e];
            atomicOr(&rowbits[(size_t)s * 64 + (d2 >> 6)], 1ull << (d2 & 63));
            atomicAdd(&deg[s], 1);
        }
        return;
    }
    int r0 = bid * RT;
    #pragma unroll
    for (int r = 0; r < RT; ++r) rows[r][d] = h[(size_t)(r0 + r) * DD + d];
    __syncthreads();
    float acc[RT];
    float b = bd[d];
    #pragma unroll
    for (int r = 0; r < RT; ++r) acc[r] = b;
    for (int kb = 0; kb < DD; kb += 16) {
        float w[16];
        #pragma unroll
        for (int j = 0; j < 16; ++j) w[j] = Wd[(size_t)(kb + j) * DD + d];
        #pragma unroll
        for (int r = 0; r < RT; ++r)
            #pragma unroll
            for (int j = 0; j < 16; ++j) acc[r] += rows[r][kb + j] * w[j];
    }
    #pragma unroll
    for (int r = 0; r < RT; ++r) h0[(size_t)(r0 + r) * DD + d] = acc[r];
    float pwd = pw[d];
    int lane = d & 63, wv = d >> 6;
    #pragma unroll
    for (int r = 0; r < RT; ++r) {
        float v = acc[r] * pwd;
        #pragma unroll
        for (int s = 32; s > 0; s >>= 1) v += __shfl_xor(v, s);
        if (lane == 0) sred[wv][r] = v;
    }
    __syncthreads();
    if (d < RT) {
        float v = sred[0][d] + sred[1][d];
        scores[r0 + d] = 1.0f / (1.0f + expf(-(v + pb[0])));
    }
}

// ---- fused: blocks [0,1024) rank ; block 1024 scan ----
__global__ void k_rank_scan(const float* __restrict__ scores, const int* __restrict__ deg,
                            int* __restrict__ keep, int* __restrict__ pos,
                            int* __restrict__ idxl, int* __restrict__ off) {
    int bid = blockIdx.x;
    int t = threadIdx.x;
    if (bid == NN / 4) {
        __shared__ int part[256];
        int base = t * 16;
        int loc[16]; int s = 0;
        #pragma unroll
        for (int i = 0; i < 16; ++i) { loc[i] = s; s += deg[base + i]; }
        part[t] = s;
        __syncthreads();
        int sum = 0;
        for (int i = 0; i < t; ++i) sum += part[i];
        #pragma unroll
        for (int i = 0; i < 16; ++i) off[base + i] = sum + loc[i];
        if (t == 255) off[NN] = sum + s;
        return;
    }
    int lane = t & 63;
    int i = bid * 4 + (t >> 6);
    float my = scores[i];
    int rank = 0;
    #pragma unroll 4
    for (int base = 0; base < NN; base += 64) {
        int jj = base + lane;
        float sj = scores[jj];
        u64 m = __ballot((sj > my) || (sj == my && jj < i));
        rank += __popcll(m);
    }
    if (lane == 0) {
        if (rank < KKEEP) { keep[i] = 1; pos[i] = rank; idxl[rank] = i; }
        else keep[i] = 0;
    }
}

// ---- fused: blocks [0,616) sub (bit-walk) ; blocks [616,1128) scatter ----
__global__ void k_sub_scatter(const u64* __restrict__ rowbits, const int* __restrict__ idxl,
                              const int* __restrict__ g, int E, const int* __restrict__ off,
                              const int* __restrict__ keep, const int* __restrict__ pos,
                              int* __restrict__ cursor, int* __restrict__ csrv,
                              ushort_t* __restrict__ S, float* __restrict__ invdeg) {
    int bid = blockIdx.x;
    int t = threadIdx.x;
    if (bid >= MP / 4) {
        int e = (bid - MP / 4) * 256 + t;
        if (e < E) {
            int s = g[e], dd = g[E + e];
            int p = atomicAdd(&cursor[s], 1);
            csrv[off[s] + p] = keep[dd] ? pos[dd] : -1;
        }
        return;
    }
    int wave = t >> 6, lane = t & 63;
    int r = bid * 4 + wave;
    ushort_t* Srow = S + (size_t)r * KP;
    if (r >= KKEEP) {
        for (int wj = 0; wj < SUBW; ++wj) Srow[wj * 64 + lane] = 0;
        return;
    }
    int i = idxl[r];
    u64 rw = rowbits[(size_t)i * 64 + lane];
    u64 acc = 0;
    for (int wm = 0; wm < 64; ++wm) {
        u64 w = __shfl(rw, wm);
        while (w) {
            int b = __builtin_ctzll(w);
            w &= w - 1;
            acc |= rowbits[(size_t)(wm * 64 + b) * 64 + lane];
        }
    }
    int cnt = 0;
    for (int wj = 0; wj < SUBW; ++wj) {
        int c = wj * 64 + lane;
        int ci = (c < KKEEP) ? idxl[c] : 0;
        u64 w = __shfl(acc, ci >> 6);
        int bit = (c < KKEEP) ? (int)((w >> (ci & 63)) & 1ull) : 0;
        cnt += __popcll(__ballot(bit));
        Srow[c] = bit ? 0x3F80 : 0;
    }
    if (lane == 0) invdeg[r] = 1.0f / (float)cnt;
}

// t'[c] = (h0[idx[c]]*scores[idx[c]]) @ Wb * invdeg[c], transposed bf16 [DD][KP].
__global__ void k_t(const float* __restrict__ h0, const float* __restrict__ scores,
                    const int* __restrict__ idxl, const float* __restrict__ Wb,
                    const float* __restrict__ invdeg, ushort_t* __restrict__ tT) {
    __shared__ float rows[RT][DD];
    int d = threadIdx.x;
    int r0 = blockIdx.x * RT;
    #pragma unroll
    for (int r = 0; r < RT; ++r) {
        int rr = r0 + r;
        float v = 0.f;
        if (rr < KKEEP) {
            int i = idxl[rr];
            v = h0[(size_t)i * DD + d] * scores[i];
        }
        rows[r][d] = v;
    }
    __syncthreads();
    float acc[RT];
    #pragma unroll
    for (int r = 0; r < RT; ++r) acc[r] = 0.f;
    for (int kb = 0; kb < DD; kb += 16) {
        float w[16];
        #pragma unroll
        for (int j = 0; j < 16; ++j) w[j] = Wb[(size_t)(kb + j) * DD + d];
        #pragma unroll
        for (int r = 0; r < RT; ++r)
            #pragma unroll
            for (int j = 0; j < 16; ++j) acc[r] += rows[r][kb + j] * w[j];
    }
    bf16x8 packed;
    #pragma unroll
    for (int r = 0; r < RT; ++r) {
        int rr = r0 + r;
        float v = (rr < KKEEP) ? acc[r] * invdeg[rr] : 0.f;
        __hip_bfloat16 b = __float2bfloat16(v);
        packed[r] = *reinterpret_cast<short*>(&b);
    }
    *reinterpret_cast<bf16x8*>(tT + (size_t)d * KP + r0) = packed;
}

// hb = S @ t' via 16x16x32 bf16 MFMA, full K per wave, direct stores.
__global__ void k_gemm(const short* __restrict__ S, const short* __restrict__ tT,
                       float* __restrict__ hb) {
    int wid = blockIdx.x * 4 + (threadIdx.x >> 6);   // 0..MT*NT-1
    int lane = threadIdx.x & 63;
    int rt = wid >> 3, ct = wid & 7;
    const short* arow = S + (size_t)(rt * 16 + (lane & 15)) * KP + ((lane >> 4) * 8);
    const short* brow = tT + (size_t)(ct * 16 + (lane & 15)) * KP + ((lane >> 4) * 8);
    f32x4 acc = {0.f, 0.f, 0.f, 0.f};
    #pragma unroll 4
    for (int kk = 0; kk < KP; kk += 32) {
        bf16x8 a = *(const bf16x8*)(arow + kk);
        bf16x8 b = *(const bf16x8*)(brow + kk);
        acc = __builtin_amdgcn_mfma_f32_16x16x32_bf16(a, b, acc, 0, 0, 0);
    }
    int col = ct * 16 + (lane & 15);
    int row0 = rt * 16 + ((lane >> 4) * 4);
    #pragma unroll
    for (int j = 0; j < 4; ++j) {
        int row = row0 + j;
        if (row < KKEEP) hb[(size_t)row * DD + col] = acc[j];
    }
}

// uu[r] = (hb[r] + bb) @ Wu
__global__ void k_u(const float* __restrict__ hb, const float* __restrict__ bb,
                    const float* __restrict__ Wu, float* __restrict__ uu) {
    __shared__ float rows[RT][DD];
    int d = threadIdx.x;
    int r0 = blockIdx.x * RT;
    float bias = bb[d];
    #pragma unroll
    for (int r = 0; r < RT; ++r) {
        int rr = r0 + r;
        rows[r][d] = (rr < KKEEP) ? hb[(size_t)rr * DD + d] + bias : 0.f;
    }
    __syncthreads();
    float acc[RT];
    #pragma unroll
    for (int r = 0; r < RT; ++r) acc[r] = 0.f;
    for (int kb = 0; kb < DD; kb += 16) {
        float w[16];
        #pragma unroll
        for (int j = 0; j < 16; ++j) w[j] = Wu[(size_t)(kb + j) * DD + d];
        #pragma unroll
        for (int r = 0; r < RT; ++r)
            #pragma unroll
            for (int j = 0; j < 16; ++j) acc[r] += rows[r][kb + j] * w[j];
    }
    #pragma unroll
    for (int r = 0; r < RT; ++r) {
        int rr = r0 + r;
        if (rr < KKEEP) uu[(size_t)rr * DD + d] = acc[r];
    }
}

// out rows: hup[s] = sum over csrv>=0 of uu rows; out1/out2 fused.
__global__ void k_agg(const int* __restrict__ off, const int* __restrict__ csrv,
                      const float* __restrict__ uu, const float* __restrict__ bu,
                      const float* __restrict__ h0, const float* __restrict__ h,
                      float* __restrict__ out) {
    int s = blockIdx.x, d = threadIdx.x;
    int b = off[s], e2 = off[s + 1];
    float acc = 0.f;
    for (int k = b; k < e2; ++k) {
        int v = csrv[k];
        if (v >= 0) acc += uu[(size_t)v * DD + d];
    }
    size_t o = (size_t)s * DD + d;
    float a = acc + bu[d] + h0[o];
    out[o] = a;
    out[(size_t)NN * DD + o] = a + h[o];
}

extern "C" void kernel_launch(void* const* d_in, const int* in_sizes, int n_in,
                              void* d_out, int out_size, void* d_ws, size_t ws_size,
                              hipStream_t stream) {
    const int*   g  = (const int*)d_in[0];
    const float* h  = (const float*)d_in[1];
    const float* Wd = (const float*)d_in[2];
    const float* bd = (const float*)d_in[3];
    const float* pw = (const float*)d_in[4];
    const float* pb = (const float*)d_in[5];
    const float* Wb = (const float*)d_in[6];
    const float* bb = (const float*)d_in[7];
    const float* Wu = (const float*)d_in[8];
    const float* bu = (const float*)d_in[9];
    float* out = (float*)d_out;
    const int E = in_sizes[0] / 2;

    char* ws = (char*)d_ws;
    // S [0, 12.6MB) live k_sub..k_gemm; uu reuses [0,1.3MB) after k_gemm.
    ushort_t* S       = (ushort_t*)(ws + 0);
    float*    uu      = (float*)(ws + 0);
    u64*      rowbits = (u64*)  (ws + (13u << 20));   // 2 MB
    int*      deg     = (int*)  (ws + (15u << 20));   // 16 KB (contig w/ rowbits)
    int*      cursor  = (int*)  (ws + (15u << 20) + 16384);
    int*      off     = (int*)  (ws + (15u << 20) + 32768); // NN+1 ints
    float*    h0      = (float*)(ws + (16u << 20));   // 2 MB
    ushort_t* tT      = (ushort_t*)(ws + (18u << 20));// 656 KB
    float*    hb      = (float*)(ws + (19u << 20));   // 1.26 MB
    int*      csrv    = (int*)  (ws + (21u << 20));   // 512 KB
    float*    scores  = (float*)(ws + (22u << 20));
    float*    invdeg  = (float*)(ws + (22u << 20) + 16384);
    int*      pos     = (int*)  (ws + (22u << 20) + 32768);
    int*      keep    = (int*)  (ws + (22u << 20) + 49152);
    int*      idxl    = (int*)  (ws + (22u << 20) + 65536);

    // one memset: rowbits (2MB) + deg (16KB) + cursor (16KB), contiguous
    (void)hipMemsetAsync(rowbits, 0, (2u << 20) + 32768, stream);

    k_h0_build<<<NN / RT + E / 128, 128, 0, stream>>>(h, Wd, bd, pw, pb, g, E,
                                                      h0, scores, rowbits, deg);
    k_rank_scan<<<NN / 4 + 1, 256, 0, stream>>>(scores, deg, keep, pos, idxl, off);
    k_sub_scatter<<<MP / 4 + E / 256, 256, 0, stream>>>(rowbits, idxl, g, E, off,
                                                        keep, pos, cursor, csrv, S, invdeg);
    k_t<<<KP / RT, DD, 0, stream>>>(h0, scores, idxl, Wb, invdeg, tT);
    k_gemm<<<(MT * NT) / 4, 256, 0, stream>>>((const short*)S, (const short*)tT, hb);
    k_u<<<(KKEEP + RT - 1) / RT, DD, 0, stream>>>(hb, bb, Wu, uu);
    k_agg<<<NN, DD, 0, stream>>>(off, csrv, uu, bu, h0, h, out);
}

// Round 10
// 149.189 us; speedup vs baseline: 1.0664x; 1.0029x over previous
//
#include <hip/hip_runtime.h>
#include <hip/hip_bf16.h>
#include <stdint.h>

// GraphUnet forward, N=4096 nodes, D=128, E=131072 edges, K=2457 kept.
// 8 dispatches: zero | h0+score||build_bits | rank||scan | sub||scatter |
// t | gemm | u | agg. Bitset 2-hop (bit-walk), dense bf16 S emission,
// full-K MFMA pooled GEMM, CSR gather up-prop fused with final adds.
// NOTE: hipMemsetAsync's fillBufferAligned ran at 50 GB/s (41 us for 2MB!)
// -> replaced with our own vectorized zero kernel (~1 us).

#define NN 4096
#define DD 128
#define KKEEP 2457              // int(0.6*4096)
#define SUBW 40                 // ceil(KKEEP/64)
#define MP 2464                 // KKEEP padded to 16 (M tiles = 154)
#define KP 2560                 // KKEEP padded to SUBW*64
#define MT 154
#define NT 8
#define RT 8                    // row tile for DxD gemms
#define ZBYTES ((2u << 20) + 32768u)   // rowbits + deg + cursor, contiguous

typedef unsigned long long u64;
typedef unsigned short ushort_t;
typedef __attribute__((ext_vector_type(8))) short bf16x8;
typedef __attribute__((ext_vector_type(4))) float f32x4;

// zero ZBYTES at base (520 blocks x 256 threads x 16B)
__global__ void k_zero(float4* __restrict__ p) {
    int i = blockIdx.x * 256 + threadIdx.x;
    p[i] = make_float4(0.f, 0.f, 0.f, 0.f);
}

// ---- fused: blocks [0,512) h0+score ; blocks [512,1536) build_bits ----
__global__ void k_h0_build(const float* __restrict__ h, const float* __restrict__ Wd,
                           const float* __restrict__ bd, const float* __restrict__ pw,
                           const float* __restrict__ pb, const int* __restrict__ g, int E,
                           float* __restrict__ h0, float* __restrict__ scores,
                           u64* __restrict__ rowbits, int* __restrict__ deg) {
    __shared__ float rows[RT][DD];
    __shared__ float sred[2][RT];
    int bid = blockIdx.x;
    int d = threadIdx.x;
    if (bid >= NN / RT) {
        int e = (bid - NN / RT) * 128 + d;
        if (e < E) {
            int s = g[e], d2 = g[E + e];
            atomicOr(&rowbits[(size_t)s * 64 + (d2 >> 6)], 1ull << (d2 & 63));
            atomicAdd(&deg[s], 1);
        }
        return;
    }
    int r0 = bid * RT;
    #pragma unroll
    for (int r = 0; r < RT; ++r) rows[r][d] = h[(size_t)(r0 + r) * DD + d];
    __syncthreads();
    float acc[RT];
    float b = bd[d];
    #pragma unroll
    for (int r = 0; r < RT; ++r) acc[r] = b;
    for (int kb = 0; kb < DD; kb += 16) {
        float w[16];
        #pragma unroll
        for (int j = 0; j < 16; ++j) w[j] = Wd[(size_t)(kb + j) * DD + d];
        #pragma unroll
        for (int r = 0; r < RT; ++r)
            #pragma unroll
            for (int j = 0; j < 16; ++j) acc[r] += rows[r][kb + j] * w[j];
    }
    #pragma unroll
    for (int r = 0; r < RT; ++r) h0[(size_t)(r0 + r) * DD + d] = acc[r];
    float pwd = pw[d];
    int lane = d & 63, wv = d >> 6;
    #pragma unroll
    for (int r = 0; r < RT; ++r) {
        float v = acc[r] * pwd;
        #pragma unroll
        for (int s = 32; s > 0; s >>= 1) v += __shfl_xor(v, s);
        if (lane == 0) sred[wv][r] = v;
    }
    __syncthreads();
    if (d < RT) {
        float v = sred[0][d] + sred[1][d];
        scores[r0 + d] = 1.0f / (1.0f + expf(-(v + pb[0])));
    }
}

// ---- fused: blocks [0,1024) rank ; block 1024 scan ----
__global__ void k_rank_scan(const float* __restrict__ scores, const int* __restrict__ deg,
                            int* __restrict__ keep, int* __restrict__ pos,
                            int* __restrict__ idxl, int* __restrict__ off) {
    int bid = blockIdx.x;
    int t = threadIdx.x;
    if (bid == NN / 4) {
        __shared__ int part[256];
        int base = t * 16;
        int loc[16]; int s = 0;
        #pragma unroll
        for (int i = 0; i < 16; ++i) { loc[i] = s; s += deg[base + i]; }
        part[t] = s;
        __syncthreads();
        int sum = 0;
        for (int i = 0; i < t; ++i) sum += part[i];
        #pragma unroll
        for (int i = 0; i < 16; ++i) off[base + i] = sum + loc[i];
        if (t == 255) off[NN] = sum + s;
        return;
    }
    int lane = t & 63;
    int i = bid * 4 + (t >> 6);
    float my = scores[i];
    int rank = 0;
    #pragma unroll 4
    for (int base = 0; base < NN; base += 64) {
        int jj = base + lane;
        float sj = scores[jj];
        u64 m = __ballot((sj > my) || (sj == my && jj < i));
        rank += __popcll(m);
    }
    if (lane == 0) {
        if (rank < KKEEP) { keep[i] = 1; pos[i] = rank; idxl[rank] = i; }
        else keep[i] = 0;
    }
}

// ---- fused: blocks [0,616) sub (bit-walk) ; blocks [616,1128) scatter ----
__global__ void k_sub_scatter(const u64* __restrict__ rowbits, const int* __restrict__ idxl,
                              const int* __restrict__ g, int E, const int* __restrict__ off,
                              const int* __restrict__ keep, const int* __restrict__ pos,
                              int* __restrict__ cursor, int* __restrict__ csrv,
                              ushort_t* __restrict__ S, float* __restrict__ invdeg) {
    int bid = blockIdx.x;
    int t = threadIdx.x;
    if (bid >= MP / 4) {
        int e = (bid - MP / 4) * 256 + t;
        if (e < E) {
            int s = g[e], dd = g[E + e];
            int p = atomicAdd(&cursor[s], 1);
            csrv[off[s] + p] = keep[dd] ? pos[dd] : -1;
        }
        return;
    }
    int wave = t >> 6, lane = t & 63;
    int r = bid * 4 + wave;
    ushort_t* Srow = S + (size_t)r * KP;
    if (r >= KKEEP) {
        for (int wj = 0; wj < SUBW; ++wj) Srow[wj * 64 + lane] = 0;
        return;
    }
    int i = idxl[r];
    u64 rw = rowbits[(size_t)i * 64 + lane];
    u64 acc = 0;
    for (int wm = 0; wm < 64; ++wm) {
        u64 w = __shfl(rw, wm);
        while (w) {
            int b = __builtin_ctzll(w);
            w &= w - 1;
            acc |= rowbits[(size_t)(wm * 64 + b) * 64 + lane];
        }
    }
    int cnt = 0;
    for (int wj = 0; wj < SUBW; ++wj) {
        int c = wj * 64 + lane;
        int ci = (c < KKEEP) ? idxl[c] : 0;
        u64 w = __shfl(acc, ci >> 6);
        int bit = (c < KKEEP) ? (int)((w >> (ci & 63)) & 1ull) : 0;
        cnt += __popcll(__ballot(bit));
        Srow[c] = bit ? 0x3F80 : 0;
    }
    if (lane == 0) invdeg[r] = 1.0f / (float)cnt;
}

// t'[c] = (h0[idx[c]]*scores[idx[c]]) @ Wb * invdeg[c], transposed bf16 [DD][KP].
__global__ void k_t(const float* __restrict__ h0, const float* __restrict__ scores,
                    const int* __restrict__ idxl, const float* __restrict__ Wb,
                    const float* __restrict__ invdeg, ushort_t* __restrict__ tT) {
    __shared__ float rows[RT][DD];
    int d = threadIdx.x;
    int r0 = blockIdx.x * RT;
    #pragma unroll
    for (int r = 0; r < RT; ++r) {
        int rr = r0 + r;
        float v = 0.f;
        if (rr < KKEEP) {
            int i = idxl[rr];
            v = h0[(size_t)i * DD + d] * scores[i];
        }
        rows[r][d] = v;
    }
    __syncthreads();
    float acc[RT];
    #pragma unroll
    for (int r = 0; r < RT; ++r) acc[r] = 0.f;
    for (int kb = 0; kb < DD; kb += 16) {
        float w[16];
        #pragma unroll
        for (int j = 0; j < 16; ++j) w[j] = Wb[(size_t)(kb + j) * DD + d];
        #pragma unroll
        for (int r = 0; r < RT; ++r)
            #pragma unroll
            for (int j = 0; j < 16; ++j) acc[r] += rows[r][kb + j] * w[j];
    }
    bf16x8 packed;
    #pragma unroll
    for (int r = 0; r < RT; ++r) {
        int rr = r0 + r;
        float v = (rr < KKEEP) ? acc[r] * invdeg[rr] : 0.f;
        __hip_bfloat16 b = __float2bfloat16(v);
        packed[r] = *reinterpret_cast<short*>(&b);
    }
    *reinterpret_cast<bf16x8*>(tT + (size_t)d * KP + r0) = packed;
}

// hb = S @ t' via 16x16x32 bf16 MFMA, full K per wave, direct stores.
__global__ void k_gemm(const short* __restrict__ S, const short* __restrict__ tT,
                       float* __restrict__ hb) {
    int wid = blockIdx.x * 4 + (threadIdx.x >> 6);   // 0..MT*NT-1
    int lane = threadIdx.x & 63;
    int rt = wid >> 3, ct = wid & 7;
    const short* arow = S + (size_t)(rt * 16 + (lane & 15)) * KP + ((lane >> 4) * 8);
    const short* brow = tT + (size_t)(ct * 16 + (lane & 15)) * KP + ((lane >> 4) * 8);
    f32x4 acc = {0.f, 0.f, 0.f, 0.f};
    #pragma unroll 4
    for (int kk = 0; kk < KP; kk += 32) {
        bf16x8 a = *(const bf16x8*)(arow + kk);
        bf16x8 b = *(const bf16x8*)(brow + kk);
        acc = __builtin_amdgcn_mfma_f32_16x16x32_bf16(a, b, acc, 0, 0, 0);
    }
    int col = ct * 16 + (lane & 15);
    int row0 = rt * 16 + ((lane >> 4) * 4);
    #pragma unroll
    for (int j = 0; j < 4; ++j) {
        int row = row0 + j;
        if (row < KKEEP) hb[(size_t)row * DD + col] = acc[j];
    }
}

// uu[r] = (hb[r] + bb) @ Wu
__global__ void k_u(const float* __restrict__ hb, const float* __restrict__ bb,
                    const float* __restrict__ Wu, float* __restrict__ uu) {
    __shared__ float rows[RT][DD];
    int d = threadIdx.x;
    int r0 = blockIdx.x * RT;
    float bias = bb[d];
    #pragma unroll
    for (int r = 0; r < RT; ++r) {
        int rr = r0 + r;
        rows[r][d] = (rr < KKEEP) ? hb[(size_t)rr * DD + d] + bias : 0.f;
    }
    __syncthreads();
    float acc[RT];
    #pragma unroll
    for (int r = 0; r < RT; ++r) acc[r] = 0.f;
    for (int kb = 0; kb < DD; kb += 16) {
        float w[16];
        #pragma unroll
        for (int j = 0; j < 16; ++j) w[j] = Wu[(size_t)(kb + j) * DD + d];
        #pragma unroll
        for (int r = 0; r < RT; ++r)
            #pragma unroll
            for (int j = 0; j < 16; ++j) acc[r] += rows[r][kb + j] * w[j];
    }
    #pragma unroll
    for (int r = 0; r < RT; ++r) {
        int rr = r0 + r;
        if (rr < KKEEP) uu[(size_t)rr * DD + d] = acc[r];
    }
}

// out rows: hup[s] = sum over csrv>=0 of uu rows; out1/out2 fused.
__global__ void k_agg(const int* __restrict__ off, const int* __restrict__ csrv,
                      const float* __restrict__ uu, const float* __restrict__ bu,
                      const float* __restrict__ h0, const float* __restrict__ h,
                      float* __restrict__ out) {
    int s = blockIdx.x, d = threadIdx.x;
    int b = off[s], e2 = off[s + 1];
    float acc = 0.f;
    for (int k = b; k < e2; ++k) {
        int v = csrv[k];
        if (v >= 0) acc += uu[(size_t)v * DD + d];
    }
    size_t o = (size_t)s * DD + d;
    float a = acc + bu[d] + h0[o];
    out[o] = a;
    out[(size_t)NN * DD + o] = a + h[o];
}

extern "C" void kernel_launch(void* const* d_in, const int* in_sizes, int n_in,
                              void* d_out, int out_size, void* d_ws, size_t ws_size,
                              hipStream_t stream) {
    const int*   g  = (const int*)d_in[0];
    const float* h  = (const float*)d_in[1];
    const float* Wd = (const float*)d_in[2];
    const float* bd = (const float*)d_in[3];
    const float* pw = (const float*)d_in[4];
    const float* pb = (const float*)d_in[5];
    const float* Wb = (const float*)d_in[6];
    const float* bb = (const float*)d_in[7];
    const float* Wu = (const float*)d_in[8];
    const float* bu = (const float*)d_in[9];
    float* out = (float*)d_out;
    const int E = in_sizes[0] / 2;

    char* ws = (char*)d_ws;
    // S [0, 12.6MB) live k_sub..k_gemm; uu reuses [0,1.3MB) after k_gemm.
    ushort_t* S       = (ushort_t*)(ws + 0);
    float*    uu      = (float*)(ws + 0);
    u64*      rowbits = (u64*)  (ws + (13u << 20));   // 2 MB
    int*      deg     = (int*)  (ws + (15u << 20));   // 16 KB (contig w/ rowbits)
    int*      cursor  = (int*)  (ws + (15u << 20) + 16384);
    int*      off     = (int*)  (ws + (15u << 20) + 32768); // NN+1 ints
    float*    h0      = (float*)(ws + (16u << 20));   // 2 MB
    ushort_t* tT      = (ushort_t*)(ws + (18u << 20));// 656 KB
    float*    hb      = (float*)(ws + (19u << 20));   // 1.26 MB
    int*      csrv    = (int*)  (ws + (21u << 20));   // 512 KB
    float*    scores  = (float*)(ws + (22u << 20));
    float*    invdeg  = (float*)(ws + (22u << 20) + 16384);
    int*      pos     = (int*)  (ws + (22u << 20) + 32768);
    int*      keep    = (int*)  (ws + (22u << 20) + 49152);
    int*      idxl    = (int*)  (ws + (22u << 20) + 65536);

    // zero rowbits (2MB) + deg (16KB) + cursor (16KB): 2129920 B = 520*256*16
    k_zero<<<520, 256, 0, stream>>>((float4*)rowbits);

    k_h0_build<<<NN / RT + E / 128, 128, 0, stream>>>(h, Wd, bd, pw, pb, g, E,
                                                      h0, scores, rowbits, deg);
    k_rank_scan<<<NN / 4 + 1, 256, 0, stream>>>(scores, deg, keep, pos, idxl, off);
    k_sub_scatter<<<MP / 4 + E / 256, 256, 0, stream>>>(rowbits, idxl, g, E, off,
                                                        keep, pos, cursor, csrv, S, invdeg);
    k_t<<<KP / RT, DD, 0, stream>>>(h0, scores, idxl, Wb, invdeg, tT);
    k_gemm<<<(MT * NT) / 4, 256, 0, stream>>>((const short*)S, (const short*)tT, hb);
    k_u<<<(KKEEP + RT - 1) / RT, DD, 0, stream>>>(hb, bb, Wu, uu);
    k_agg<<<NN, DD, 0, stream>>>(off, csrv, uu, bu, h0, h, out);
}

// Round 11
// 123.845 us; speedup vs baseline: 1.2846x; 1.2046x over previous
//
#include <hip/hip_runtime.h>
#include <hip/hip_bf16.h>
#include <stdint.h>

// GraphUnet forward, N=4096 nodes, D=128, E=131072 edges, K=2457 kept.
// 8 dispatches: zero | h0+score||build_bits | rank||scan | sub||scatter |
// t | gemm | u | agg.
// R11: k_sub = 1 block (4 waves) per row, LDS neighbor list + parallel
// union (4x shorter serial chain); k_gemm = block split-K=4 + LDS reduce
// (4.8 waves/SIMD); k_agg unrolled gather.

#define NN 4096
#define DD 128
#define KKEEP 2457              // int(0.6*4096)
#define SUBW 40                 // ceil(KKEEP/64)
#define MP 2464                 // KKEEP padded to 16 (M tiles = 154)
#define KP 2560                 // KKEEP padded to SUBW*64
#define MT 154
#define NT 8
#define KCHUNK (KP / 4)         // 640: K-range per wave in k_gemm
#define RT 8                    // row tile for DxD gemms

typedef unsigned long long u64;
typedef unsigned short ushort_t;
typedef __attribute__((ext_vector_type(8))) short bf16x8;
typedef __attribute__((ext_vector_type(4))) float f32x4;

// zero rowbits+deg+cursor (520 blocks x 256 threads x 16B = 2129920 B)
__global__ void k_zero(float4* __restrict__ p) {
    int i = blockIdx.x * 256 + threadIdx.x;
    p[i] = make_float4(0.f, 0.f, 0.f, 0.f);
}

// ---- fused: blocks [0,512) h0+score ; blocks [512,1536) build_bits ----
__global__ void k_h0_build(const float* __restrict__ h, const float* __restrict__ Wd,
                           const float* __restrict__ bd, const float* __restrict__ pw,
                           const float* __restrict__ pb, const int* __restrict__ g, int E,
                           float* __restrict__ h0, float* __restrict__ scores,
                           u64* __restrict__ rowbits, int* __restrict__ deg) {
    __shared__ float rows[RT][DD];
    __shared__ float sred[2][RT];
    int bid = blockIdx.x;
    int d = threadIdx.x;
    if (bid >= NN / RT) {
        int e = (bid - NN / RT) * 128 + d;
        if (e < E) {
            int s = g[e], d2 = g[E + e];
            atomicOr(&rowbits[(size_t)s * 64 + (d2 >> 6)], 1ull << (d2 & 63));
            atomicAdd(&deg[s], 1);
        }
        return;
    }
    int r0 = bid * RT;
    #pragma unroll
    for (int r = 0; r < RT; ++r) rows[r][d] = h[(size_t)(r0 + r) * DD + d];
    __syncthreads();
    float acc[RT];
    float b = bd[d];
    #pragma unroll
    for (int r = 0; r < RT; ++r) acc[r] = b;
    for (int kb = 0; kb < DD; kb += 16) {
        float w[16];
        #pragma unroll
        for (int j = 0; j < 16; ++j) w[j] = Wd[(size_t)(kb + j) * DD + d];
        #pragma unroll
        for (int r = 0; r < RT; ++r)
            #pragma unroll
            for (int j = 0; j < 16; ++j) acc[r] += rows[r][kb + j] * w[j];
    }
    #pragma unroll
    for (int r = 0; r < RT; ++r) h0[(size_t)(r0 + r) * DD + d] = acc[r];
    float pwd = pw[d];
    int lane = d & 63, wv = d >> 6;
    #pragma unroll
    for (int r = 0; r < RT; ++r) {
        float v = acc[r] * pwd;
        #pragma unroll
        for (int s = 32; s > 0; s >>= 1) v += __shfl_xor(v, s);
        if (lane == 0) sred[wv][r] = v;
    }
    __syncthreads();
    if (d < RT) {
        float v = sred[0][d] + sred[1][d];
        scores[r0 + d] = 1.0f / (1.0f + expf(-(v + pb[0])));
    }
}

// ---- fused: blocks [0,1024) rank ; block 1024 scan ----
__global__ void k_rank_scan(const float* __restrict__ scores, const int* __restrict__ deg,
                            int* __restrict__ keep, int* __restrict__ pos,
                            int* __restrict__ idxl, int* __restrict__ off) {
    int bid = blockIdx.x;
    int t = threadIdx.x;
    if (bid == NN / 4) {
        __shared__ int part[256];
        int base = t * 16;
        int loc[16]; int s = 0;
        #pragma unroll
        for (int i = 0; i < 16; ++i) { loc[i] = s; s += deg[base + i]; }
        part[t] = s;
        __syncthreads();
        int sum = 0;
        for (int i = 0; i < t; ++i) sum += part[i];
        #pragma unroll
        for (int i = 0; i < 16; ++i) off[base + i] = sum + loc[i];
        if (t == 255) off[NN] = sum + s;
        return;
    }
    int lane = t & 63;
    int i = bid * 4 + (t >> 6);
    float my = scores[i];
    int rank = 0;
    #pragma unroll 4
    for (int base = 0; base < NN; base += 64) {
        int jj = base + lane;
        float sj = scores[jj];
        u64 m = __ballot((sj > my) || (sj == my && jj < i));
        rank += __popcll(m);
    }
    if (lane == 0) {
        if (rank < KKEEP) { keep[i] = 1; pos[i] = rank; idxl[rank] = i; }
        else keep[i] = 0;
    }
}

// ---- fused: blocks [0,MP) sub (1 block/row, 4-wave parallel union) ;
//             blocks [MP, MP+512) scatter ----
__global__ void k_sub_scatter(const u64* __restrict__ rowbits, const int* __restrict__ idxl,
                              const int* __restrict__ g, int E, const int* __restrict__ off,
                              const int* __restrict__ keep, const int* __restrict__ pos,
                              int* __restrict__ cursor, int* __restrict__ csrv,
                              ushort_t* __restrict__ S, float* __restrict__ invdeg) {
    __shared__ int nb[320];
    __shared__ int nbcnt;
    __shared__ int cntS;
    __shared__ u64 accLDS[64];
    int bid = blockIdx.x;
    int t = threadIdx.x;
    if (bid >= MP) {
        int e = (bid - MP) * 256 + t;
        if (e < E) {
            int s = g[e], dd = g[E + e];
            int p = atomicAdd(&cursor[s], 1);
            csrv[off[s] + p] = keep[dd] ? pos[dd] : -1;
        }
        return;
    }
    int r = bid;
    int wv = t >> 6, lane = t & 63;
    ushort_t* Srow = S + (size_t)r * KP;
    if (r >= KKEEP) {
        // zero pad row: 2560 shorts / 256 threads = 10 each
        #pragma unroll
        for (int j = 0; j < 10; ++j) Srow[j * 256 + t] = 0;
        return;
    }
    int i = idxl[r];
    if (wv == 0) {
        // extract neighbor list (set bits of row i) via wave prefix scan
        u64 rw = rowbits[(size_t)i * 64 + lane];
        int myc = __popcll(rw);
        int pre = myc;
        #pragma unroll
        for (int s = 1; s < 64; s <<= 1) {
            int tt = __shfl_up(pre, s);
            if (lane >= s) pre += tt;
        }
        pre -= myc;                      // exclusive prefix
        u64 w = rw; int j = 0;
        while (w) {
            int b = __builtin_ctzll(w);
            w &= w - 1;
            nb[pre + j] = lane * 64 + b; ++j;
        }
        if (lane == 63) nbcnt = pre + myc;
    } else if (wv == 1) {
        accLDS[lane] = 0;
    } else if (wv == 2 && lane == 0) {
        cntS = 0;
    }
    __syncthreads();
    // parallel union: wave wv takes neighbors wv, wv+4, wv+8, ...
    int cnt_nb = nbcnt;
    u64 accw = 0;
    for (int j = wv; j < cnt_nb; j += 4)
        accw |= rowbits[(size_t)nb[j] * 64 + lane];
    atomicOr(&accLDS[lane], accw);
    __syncthreads();
    // projection: wave wv covers wj in [wv*10, wv*10+10)
    int cntp = 0;
    #pragma unroll
    for (int wjj = 0; wjj < 10; ++wjj) {
        int wj = wv * 10 + wjj;
        int c = wj * 64 + lane;
        int ci = (c < KKEEP) ? idxl[c] : 0;
        u64 w = accLDS[ci >> 6];
        int bit = (c < KKEEP) ? (int)((w >> (ci & 63)) & 1ull) : 0;
        cntp += __popcll(__ballot(bit));
        Srow[c] = bit ? 0x3F80 : 0;
    }
    if (lane == 0) atomicAdd(&cntS, cntp);
    __syncthreads();
    if (t == 0) invdeg[r] = 1.0f / (float)cntS;
}

// t'[c] = (h0[idx[c]]*scores[idx[c]]) @ Wb * invdeg[c], transposed bf16 [DD][KP].
__global__ void k_t(const float* __restrict__ h0, const float* __restrict__ scores,
                    const int* __restrict__ idxl, const float* __restrict__ Wb,
                    const float* __restrict__ invdeg, ushort_t* __restrict__ tT) {
    __shared__ float rows[RT][DD];
    int d = threadIdx.x;
    int r0 = blockIdx.x * RT;
    #pragma unroll
    for (int r = 0; r < RT; ++r) {
        int rr = r0 + r;
        float v = 0.f;
        if (rr < KKEEP) {
            int i = idxl[rr];
            v = h0[(size_t)i * DD + d] * scores[i];
        }
        rows[r][d] = v;
    }
    __syncthreads();
    float acc[RT];
    #pragma unroll
    for (int r = 0; r < RT; ++r) acc[r] = 0.f;
    for (int kb = 0; kb < DD; kb += 16) {
        float w[16];
        #pragma unroll
        for (int j = 0; j < 16; ++j) w[j] = Wb[(size_t)(kb + j) * DD + d];
        #pragma unroll
        for (int r = 0; r < RT; ++r)
            #pragma unroll
            for (int j = 0; j < 16; ++j) acc[r] += rows[r][kb + j] * w[j];
    }
    bf16x8 packed;
    #pragma unroll
    for (int r = 0; r < RT; ++r) {
        int rr = r0 + r;
        float v = (rr < KKEEP) ? acc[r] * invdeg[rr] : 0.f;
        __hip_bfloat16 b = __float2bfloat16(v);
        packed[r] = *reinterpret_cast<short*>(&b);
    }
    *reinterpret_cast<bf16x8*>(tT + (size_t)d * KP + r0) = packed;
}

// hb = S @ t': one block per 16x16 tile, 4 waves = 4 K-chunks, LDS reduce.
__global__ void k_gemm(const short* __restrict__ S, const short* __restrict__ tT,
                       float* __restrict__ hb) {
    __shared__ f32x4 red[4][64];
    int tile = blockIdx.x;                       // 0..MT*NT-1
    int wv = threadIdx.x >> 6, lane = threadIdx.x & 63;
    int rt = tile >> 3, ct = tile & 7;
    const short* arow = S + (size_t)(rt * 16 + (lane & 15)) * KP + ((lane >> 4) * 8) + wv * KCHUNK;
    const short* brow = tT + (size_t)(ct * 16 + (lane & 15)) * KP + ((lane >> 4) * 8) + wv * KCHUNK;
    f32x4 acc = {0.f, 0.f, 0.f, 0.f};
    #pragma unroll 4
    for (int kk = 0; kk < KCHUNK; kk += 32) {
        bf16x8 a = *(const bf16x8*)(arow + kk);
        bf16x8 b = *(const bf16x8*)(brow + kk);
        acc = __builtin_amdgcn_mfma_f32_16x16x32_bf16(a, b, acc, 0, 0, 0);
    }
    red[wv][lane] = acc;
    __syncthreads();
    if (wv == 0) {
        f32x4 s = red[0][lane] + red[1][lane] + red[2][lane] + red[3][lane];
        int col = ct * 16 + (lane & 15);
        int row0 = rt * 16 + ((lane >> 4) * 4);
        #pragma unroll
        for (int j = 0; j < 4; ++j) {
            int row = row0 + j;
            if (row < KKEEP) hb[(size_t)row * DD + col] = s[j];
        }
    }
}

// uu[r] = (hb[r] + bb) @ Wu
__global__ void k_u(const float* __restrict__ hb, const float* __restrict__ bb,
                    const float* __restrict__ Wu, float* __restrict__ uu) {
    __shared__ float rows[RT][DD];
    int d = threadIdx.x;
    int r0 = blockIdx.x * RT;
    float bias = bb[d];
    #pragma unroll
    for (int r = 0; r < RT; ++r) {
        int rr = r0 + r;
        rows[r][d] = (rr < KKEEP) ? hb[(size_t)rr * DD + d] + bias : 0.f;
    }
    __syncthreads();
    float acc[RT];
    #pragma unroll
    for (int r = 0; r < RT; ++r) acc[r] = 0.f;
    for (int kb = 0; kb < DD; kb += 16) {
        float w[16];
        #pragma unroll
        for (int j = 0; j < 16; ++j) w[j] = Wu[(size_t)(kb + j) * DD + d];
        #pragma unroll
        for (int r = 0; r < RT; ++r)
            #pragma unroll
            for (int j = 0; j < 16; ++j) acc[r] += rows[r][kb + j] * w[j];
    }
    #pragma unroll
    for (int r = 0; r < RT; ++r) {
        int rr = r0 + r;
        if (rr < KKEEP) uu[(size_t)rr * DD + d] = acc[r];
    }
}

// out rows: hup[s] = sum over csrv>=0 of uu rows; out1/out2 fused.
__global__ void k_agg(const int* __restrict__ off, const int* __restrict__ csrv,
                      const float* __restrict__ uu, const float* __restrict__ bu,
                      const float* __restrict__ h0, const float* __restrict__ h,
                      float* __restrict__ out) {
    int s = blockIdx.x, d = threadIdx.x;
    int b = off[s], e2 = off[s + 1];
    float acc = 0.f;
    int k = b;
    for (; k + 4 <= e2; k += 4) {
        int v0 = csrv[k], v1 = csrv[k + 1], v2 = csrv[k + 2], v3 = csrv[k + 3];
        float a0 = (v0 >= 0) ? uu[(size_t)v0 * DD + d] : 0.f;
        float a1 = (v1 >= 0) ? uu[(size_t)v1 * DD + d] : 0.f;
        float a2 = (v2 >= 0) ? uu[(size_t)v2 * DD + d] : 0.f;
        float a3 = (v3 >= 0) ? uu[(size_t)v3 * DD + d] : 0.f;
        acc += (a0 + a1) + (a2 + a3);
    }
    for (; k < e2; ++k) {
        int v = csrv[k];
        if (v >= 0) acc += uu[(size_t)v * DD + d];
    }
    size_t o = (size_t)s * DD + d;
    float a = acc + bu[d] + h0[o];
    out[o] = a;
    out[(size_t)NN * DD + o] = a + h[o];
}

extern "C" void kernel_launch(void* const* d_in, const int* in_sizes, int n_in,
                              void* d_out, int out_size, void* d_ws, size_t ws_size,
                              hipStream_t stream) {
    const int*   g  = (const int*)d_in[0];
    const float* h  = (const float*)d_in[1];
    const float* Wd = (const float*)d_in[2];
    const float* bd = (const float*)d_in[3];
    const float* pw = (const float*)d_in[4];
    const float* pb = (const float*)d_in[5];
    const float* Wb = (const float*)d_in[6];
    const float* bb = (const float*)d_in[7];
    const float* Wu = (const float*)d_in[8];
    const float* bu = (const float*)d_in[9];
    float* out = (float*)d_out;
    const int E = in_sizes[0] / 2;

    char* ws = (char*)d_ws;
    // S [0, 12.6MB) live k_sub..k_gemm; uu reuses [0,1.3MB) after k_gemm.
    ushort_t* S       = (ushort_t*)(ws + 0);
    float*    uu      = (float*)(ws + 0);
    u64*      rowbits = (u64*)  (ws + (13u << 20));   // 2 MB
    int*      deg     = (int*)  (ws + (15u << 20));   // 16 KB (contig w/ rowbits)
    int*      cursor  = (int*)  (ws + (15u << 20) + 16384);
    int*      off     = (int*)  (ws + (15u << 20) + 32768); // NN+1 ints
    float*    h0      = (float*)(ws + (16u << 20));   // 2 MB
    ushort_t* tT      = (ushort_t*)(ws + (18u << 20));// 656 KB
    float*    hb      = (float*)(ws + (19u << 20));   // 1.26 MB
    int*      csrv    = (int*)  (ws + (21u << 20));   // 512 KB
    float*    scores  = (float*)(ws + (22u << 20));
    float*    invdeg  = (float*)(ws + (22u << 20) + 16384);
    int*      pos     = (int*)  (ws + (22u << 20) + 32768);
    int*      keep    = (int*)  (ws + (22u << 20) + 49152);
    int*      idxl    = (int*)  (ws + (22u << 20) + 65536);

    k_zero<<<520, 256, 0, stream>>>((float4*)rowbits);

    k_h0_build<<<NN / RT + E / 128, 128, 0, stream>>>(h, Wd, bd, pw, pb, g, E,
                                                      h0, scores, rowbits, deg);
    k_rank_scan<<<NN / 4 + 1, 256, 0, stream>>>(scores, deg, keep, pos, idxl, off);
    k_sub_scatter<<<MP + E / 256, 256, 0, stream>>>(rowbits, idxl, g, E, off,
                                                    keep, pos, cursor, csrv, S, invdeg);
    k_t<<<KP / RT, DD, 0, stream>>>(h0, scores, idxl, Wb, invdeg, tT);
    k_gemm<<<MT * NT, 256, 0, stream>>>((const short*)S, (const short*)tT, hb);
    k_u<<<(KKEEP + RT - 1) / RT, DD, 0, stream>>>(hb, bb, Wu, uu);
    k_agg<<<NN, DD, 0, stream>>>(off, csrv, uu, bu, h0, h, out);
}